// Round 1
// baseline (240.389 us; speedup 1.0000x reference)
//
#include <hip/hip_runtime.h>

#define TOPK 10
#define CLIP 0.05f
#define EPSV 1e-8f
#define ALPHA1 2.0f
#define ALPHA_OTHER 0.5f

// sortable packed key: (monotone float key << 32) | (C - col)
// larger packed = larger value; on equal value, smaller col wins (matches lax.top_k)
__device__ __forceinline__ unsigned long long pack_vc(float v, int c, int C) {
  unsigned u = __float_as_uint(v);
  unsigned key = (u & 0x80000000u) ? ~u : (u | 0x80000000u);
  return ((unsigned long long)key << 32) | (unsigned)(C - c);
}
__device__ __forceinline__ float unpack_v(unsigned long long p) {
  unsigned key = (unsigned)(p >> 32);
  unsigned u = (key & 0x80000000u) ? (key & 0x7fffffffu) : ~key;
  return __uint_as_float(u);
}
__device__ __forceinline__ int unpack_c(unsigned long long p, int C) {
  return C - (int)(unsigned)(p & 0xffffffffu);
}

// base * w for one element. pos = (y == 1)
__device__ __forceinline__ float base_w(float xv, bool pos) {
  float p = 1.f / (1.f + __expf(-xv));          // sigmoid
  float xneg = fminf(1.f - p + CLIP, 1.f);
  float q = pos ? p : xneg;
  float b = __logf(fmaxf(q, EPSV));
  float t = 1.f - q;                             // 1 - pt
  float t2 = t * t;
  float w = pos ? t : t2 * t2;                   // gamma: pos=1, neg=4
  return b * w;
}

__global__ __launch_bounds__(256) void asl_kernel(
    const float* __restrict__ x, const float* __restrict__ y,
    const int* __restrict__ compost, const int* __restrict__ recycle,
    const int* __restrict__ donate, const int* __restrict__ wl_map,
    float* __restrict__ out, int C, int n1, int n2, int n3)
{
  const int row = blockIdx.x;
  const float* xr = x + (size_t)row * (size_t)C;
  const float* yr = y + (size_t)row * (size_t)C;
  const int tid = threadIdx.x;
  const int lane = tid & 63;
  const int wave = tid >> 6;

  __shared__ int s_has[3];
  __shared__ unsigned long long s_wl[4][TOPK];
  __shared__ float s_sum[4];

  if (tid < 3) s_has[tid] = 0;
  __syncthreads();

  // per-row whitelist presence flags (benign write-1 races)
  const int ntot = n1 + n2 + n3;
  for (int i = tid; i < ntot; i += 256) {
    int which, colI;
    if (i < n1)            { which = 0; colI = compost[i]; }
    else if (i < n1 + n2)  { which = 1; colI = recycle[i - n1]; }
    else                   { which = 2; colI = donate[i - n1 - n2]; }
    if (yr[colI] > 0.5f) s_has[which] = 1;
  }

  // per-thread sorted top-10 (registers only: all indices static)
  float lv[TOPK]; int lc[TOPK];
#pragma unroll
  for (int s = 0; s < TOPK; s++) { lv[s] = -__builtin_inff(); lc[s] = 0; }

  float sum = 0.f;
  for (int col = tid; col < C; col += 256) {
    float xv = xr[col];
    float yv = yr[col];
    sum += base_w(xv, yv > 0.5f);
    if (xv > lv[TOPK - 1]) {
      float v = xv; int c = col;
#pragma unroll
      for (int s = 0; s < TOPK; s++) {
        bool g = v > lv[s];
        float tv = g ? lv[s] : v; int tc = g ? lc[s] : c;
        lv[s] = g ? v : lv[s];   lc[s] = g ? c : lc[s];
        v = tv; c = tc;
      }
    }
  }

  // wave reduce the sum
#pragma unroll
  for (int off = 32; off > 0; off >>= 1) sum += __shfl_xor(sum, off, 64);
  if (lane == 0) s_sum[wave] = sum;

  // wave-level top-10 extraction: 10 rounds of 64-lane packed max
  for (int r = 0; r < TOPK; r++) {
    unsigned long long mine = pack_vc(lv[0], lc[0], C);
    unsigned long long best = mine;
#pragma unroll
    for (int off = 32; off > 0; off >>= 1) {
      unsigned long long o = __shfl_xor(best, off, 64);
      best = (o > best) ? o : best;
    }
    if (lane == 0) s_wl[wave][r] = best;
    if (mine == best) {  // exactly one lane (cols unique); pop head by shifting
#pragma unroll
      for (int s = 0; s < TOPK - 1; s++) { lv[s] = lv[s + 1]; lc[s] = lc[s + 1]; }
      lv[TOPK - 1] = -__builtin_inff(); lc[TOPK - 1] = 0;
    }
  }
  __syncthreads();

  if (tid == 0) {
    float total = s_sum[0] + s_sum[1] + s_sum[2] + s_sum[3];
    const bool h1 = s_has[0] != 0, h2 = s_has[1] != 0, h3 = s_has[2] != 0;
    const bool gt4 = !(h1 || h2 || h3);

    // merge 4 sorted wave lists -> global top-10 (descending)
    unsigned long long top[TOPK];
    int p0 = 0, p1 = 0, p2 = 0, p3 = 0;
#pragma unroll
    for (int r = 0; r < TOPK; r++) {
      unsigned long long v0 = (p0 < TOPK) ? s_wl[0][p0] : 0ULL;
      unsigned long long v1 = (p1 < TOPK) ? s_wl[1][p1] : 0ULL;
      unsigned long long v2 = (p2 < TOPK) ? s_wl[2][p2] : 0ULL;
      unsigned long long v3 = (p3 < TOPK) ? s_wl[3][p3] : 0ULL;
      unsigned long long bv = v0; int bw_ = 0;
      if (v1 > bv) { bv = v1; bw_ = 1; }
      if (v2 > bv) { bv = v2; bw_ = 2; }
      if (v3 > bv) { bv = v3; bw_ = 3; }
      top[r] = bv;
      if (bw_ == 0) p0++; else if (bw_ == 1) p1++; else if (bw_ == 2) p2++; else p3++;
    }

    // rank-sequential multiplier logic (mirrors the lax.scan)
    bool found = false;
    float fr[TOPK];
#pragma unroll
    for (int r = 0; r < TOPK; r++) {
      int col = unpack_c(top[r], C);
      int wl = wl_map[col];
      bool in_map = wl > 0;
      bool in_gt = (wl == 1 && h1) || (wl == 2 && h2) ||
                   (wl == 3 && h3) || (wl == 4 && gt4);
      float f = 1.f;
      if (in_map && gt4) f *= ALPHA_OTHER;
      if (in_map && !in_gt && !found) f *= ALPHA1;
      fr[r] = f;
      found = found || (in_map && in_gt);
    }
    const float extra = found ? 1.f : ALPHA1;
#pragma unroll
    for (int r = 0; r < TOPK; r++) {
      float mult = fr[r] * extra;
      if (mult != 1.f) {
        int col = unpack_c(top[r], C);
        float xv = unpack_v(top[r]);
        float bwv = base_w(xv, yr[col] > 0.5f);
        total += (mult - 1.f) * bwv;
      }
    }
    atomicAdd(out, -total);
  }
}

extern "C" void kernel_launch(void* const* d_in, const int* in_sizes, int n_in,
                              void* d_out, int out_size, void* d_ws, size_t ws_size,
                              hipStream_t stream) {
  const float* x       = (const float*)d_in[0];
  const float* y       = (const float*)d_in[1];
  const int*   compost = (const int*)d_in[2];
  const int*   recycle = (const int*)d_in[3];
  const int*   donate  = (const int*)d_in[4];
  const int*   wl_map  = (const int*)d_in[5];
  float* out = (float*)d_out;

  const int C  = in_sizes[5];
  const int B  = in_sizes[0] / C;
  const int n1 = in_sizes[2], n2 = in_sizes[3], n3 = in_sizes[4];

  hipMemsetAsync(out, 0, sizeof(float), stream);
  asl_kernel<<<B, 256, 0, stream>>>(x, y, compost, recycle, donate, wl_map,
                                    out, C, n1, n2, n3);
}

// Round 2
// 214.237 us; speedup vs baseline: 1.1221x; 1.1221x over previous
//
#include <hip/hip_runtime.h>

#define TOPK 10
#define CLIP 0.05f
#define EPSV 1e-8f
#define ALPHA1 2.0f
#define ALPHA_OTHER 0.5f
#define TCAND 2.5f     // candidate threshold; guarded by exact fallback
#define MAXC 512

// sortable packed key: (monotone float key << 32) | (C - col)
// larger packed = larger value; on equal value, smaller col wins (matches lax.top_k)
__device__ __forceinline__ unsigned long long pack_vc(float v, int c, int C) {
  unsigned u = __float_as_uint(v);
  unsigned key = (u & 0x80000000u) ? ~u : (u | 0x80000000u);
  return ((unsigned long long)key << 32) | (unsigned)(C - c);
}
__device__ __forceinline__ float unpack_v(unsigned long long p) {
  unsigned key = (unsigned)(p >> 32);
  unsigned u = (key & 0x80000000u) ? (key & 0x7fffffffu) : ~key;
  return __uint_as_float(u);
}
__device__ __forceinline__ int unpack_c(unsigned long long p, int C) {
  return C - (int)(unsigned)(p & 0xffffffffu);
}

// base * w for one element. pos = (y == 1)
__device__ __forceinline__ float base_w(float xv, bool pos) {
  float p = 1.f / (1.f + __expf(-xv));          // sigmoid
  float xneg = fminf(1.f - p + CLIP, 1.f);
  float q = pos ? p : xneg;
  float b = __logf(fmaxf(q, EPSV));
  float t = 1.f - q;                             // 1 - pt
  float t2 = t * t;
  float w = pos ? t : t2 * t2;                   // gamma: pos=1, neg=4
  return b * w;
}

__global__ __launch_bounds__(256) void asl_kernel(
    const float* __restrict__ x, const float* __restrict__ y,
    const int* __restrict__ compost, const int* __restrict__ recycle,
    const int* __restrict__ donate, const int* __restrict__ wl_map,
    float* __restrict__ out, int C, int n1, int n2, int n3)
{
  const int row = blockIdx.x;
  const float* xr = x + (size_t)row * (size_t)C;
  const float* yr = y + (size_t)row * (size_t)C;
  const int tid = threadIdx.x;
  const int lane = tid & 63;
  const int wave = tid >> 6;

  __shared__ int s_has[3];
  __shared__ unsigned s_cnt;
  __shared__ unsigned long long s_cand[MAXC];
  __shared__ float s_sum[4];
  __shared__ unsigned long long s_top[TOPK];

  if (tid < 3) s_has[tid] = 0;
  if (tid == 0) s_cnt = 0;
  __syncthreads();

  // per-row whitelist presence flags (benign write-1 races)
  const int ntot = n1 + n2 + n3;
  for (int i = tid; i < ntot; i += 256) {
    int which, colI;
    if (i < n1)            { which = 0; colI = compost[i]; }
    else if (i < n1 + n2)  { which = 1; colI = recycle[i - n1]; }
    else                   { which = 2; colI = donate[i - n1 - n2]; }
    if (yr[colI] > 0.5f) s_has[which] = 1;
  }

  float sum = 0.f;
#define PROCESS(XV, YV, COL)                                              \
  do {                                                                    \
    float _xv = (XV);                                                     \
    sum += base_w(_xv, (YV) > 0.5f);                                      \
    if (_xv > TCAND) {                                                    \
      unsigned _i = atomicAdd(&s_cnt, 1u);                                \
      if (_i < MAXC) s_cand[_i] = pack_vc(_xv, (COL), C);                 \
    }                                                                     \
  } while (0)

  // alignment prologue: make float4 base 16B-aligned (row*C mod 4 varies)
  int lead = (int)((4u - ((unsigned)((size_t)row * (size_t)C) & 3u)) & 3u);
  if (lead > C) lead = C;
  for (int col = tid; col < lead; col += 256) PROCESS(xr[col], yr[col], col);

  const int nvec = (C - lead) >> 2;
  const float4* __restrict__ x4 = (const float4*)(xr + lead);
  const float4* __restrict__ y4 = (const float4*)(yr + lead);
  for (int i = tid; i < nvec; i += 256) {
    float4 xv = x4[i];
    float4 yv = y4[i];
    int cb = lead + i * 4;
    PROCESS(xv.x, yv.x, cb + 0);
    PROCESS(xv.y, yv.y, cb + 1);
    PROCESS(xv.z, yv.z, cb + 2);
    PROCESS(xv.w, yv.w, cb + 3);
  }
  for (int col = lead + nvec * 4 + tid; col < C; col += 256)
    PROCESS(xr[col], yr[col], col);
#undef PROCESS

  // wave reduce the sum
#pragma unroll
  for (int off = 32; off > 0; off >>= 1) sum += __shfl_xor(sum, off, 64);
  if (lane == 0) s_sum[wave] = sum;
  __syncthreads();

  // wave 0: exact top-10 selection
  if (wave == 0) {
    const unsigned cnt = s_cnt;
    unsigned long long ls[TOPK];   // per-lane sorted (desc) packed list; 0 = pad
#pragma unroll
    for (int s = 0; s < TOPK; s++) ls[s] = 0ULL;

#define INSERT(P)                                                          \
    do {                                                                   \
      unsigned long long _p = (P);                                         \
      if (_p > ls[TOPK - 1]) {                                             \
        _Pragma("unroll")                                                  \
        for (int _s = 0; _s < TOPK; _s++) {                                \
          bool _g = _p > ls[_s];                                           \
          unsigned long long _t = _g ? ls[_s] : _p;                        \
          ls[_s] = _g ? _p : ls[_s];                                       \
          _p = _t;                                                         \
        }                                                                  \
      }                                                                    \
    } while (0)

    if (cnt >= TOPK && cnt <= MAXC) {
      for (unsigned i = lane; i < cnt; i += 64) INSERT(s_cand[i]);
    } else {
      // exact fallback: rescan the (cache-resident) row
      for (int col = lane; col < C; col += 64) INSERT(pack_vc(xr[col], col, C));
    }
#undef INSERT

    // 10 rounds of 64-lane packed max; pop winner (packed values unique)
    for (int r = 0; r < TOPK; r++) {
      unsigned long long mine = ls[0];
      unsigned long long best = mine;
#pragma unroll
      for (int off = 32; off > 0; off >>= 1) {
        unsigned long long o = __shfl_xor(best, off, 64);
        best = (o > best) ? o : best;
      }
      if (lane == 0) s_top[r] = best;
      if (mine == best) {
#pragma unroll
        for (int s = 0; s < TOPK - 1; s++) ls[s] = ls[s + 1];
        ls[TOPK - 1] = 0ULL;
      }
    }
  }
  __syncthreads();

  if (tid == 0) {
    float total = s_sum[0] + s_sum[1] + s_sum[2] + s_sum[3];
    const bool h1 = s_has[0] != 0, h2 = s_has[1] != 0, h3 = s_has[2] != 0;
    const bool gt4 = !(h1 || h2 || h3);

    // rank-sequential multiplier logic (mirrors the lax.scan)
    bool found = false;
    float fr[TOPK];
#pragma unroll
    for (int r = 0; r < TOPK; r++) {
      int col = unpack_c(s_top[r], C);
      int wl = wl_map[col];
      bool in_map = wl > 0;
      bool in_gt = (wl == 1 && h1) || (wl == 2 && h2) ||
                   (wl == 3 && h3) || (wl == 4 && gt4);
      float f = 1.f;
      if (in_map && gt4) f *= ALPHA_OTHER;
      if (in_map && !in_gt && !found) f *= ALPHA1;
      fr[r] = f;
      found = found || (in_map && in_gt);
    }
    const float extra = found ? 1.f : ALPHA1;
#pragma unroll
    for (int r = 0; r < TOPK; r++) {
      float mult = fr[r] * extra;
      if (mult != 1.f) {
        int col = unpack_c(s_top[r], C);
        float xv = unpack_v(s_top[r]);
        float bwv = base_w(xv, yr[col] > 0.5f);
        total += (mult - 1.f) * bwv;
      }
    }
    atomicAdd(out, -total);
  }
}

extern "C" void kernel_launch(void* const* d_in, const int* in_sizes, int n_in,
                              void* d_out, int out_size, void* d_ws, size_t ws_size,
                              hipStream_t stream) {
  const float* x       = (const float*)d_in[0];
  const float* y       = (const float*)d_in[1];
  const int*   compost = (const int*)d_in[2];
  const int*   recycle = (const int*)d_in[3];
  const int*   donate  = (const int*)d_in[4];
  const int*   wl_map  = (const int*)d_in[5];
  float* out = (float*)d_out;

  const int C  = in_sizes[5];
  const int B  = in_sizes[0] / C;
  const int n1 = in_sizes[2], n2 = in_sizes[3], n3 = in_sizes[4];

  hipMemsetAsync(out, 0, sizeof(float), stream);
  asl_kernel<<<B, 256, 0, stream>>>(x, y, compost, recycle, donate, wl_map,
                                    out, C, n1, n2, n3);
}

// Round 3
// 205.787 us; speedup vs baseline: 1.1681x; 1.0411x over previous
//
#include <hip/hip_runtime.h>

#define TOPK 10
#define CLIP 0.05f
#define EPSV 1e-8f
#define ALPHA1 2.0f
#define ALPHA_OTHER 0.5f
#define TCAND 2.5f     // candidate threshold; guarded by exact fallback
#define MAXC 512

// sortable packed key: (monotone float key << 32) | (C - col)
// larger packed = larger value; on equal value, smaller col wins (matches lax.top_k)
__device__ __forceinline__ unsigned long long pack_vc(float v, int c, int C) {
  unsigned u = __float_as_uint(v);
  unsigned key = (u & 0x80000000u) ? ~u : (u | 0x80000000u);
  return ((unsigned long long)key << 32) | (unsigned)(C - c);
}
__device__ __forceinline__ float unpack_v(unsigned long long p) {
  unsigned key = (unsigned)(p >> 32);
  unsigned u = (key & 0x80000000u) ? (key & 0x7fffffffu) : ~key;
  return __uint_as_float(u);
}
__device__ __forceinline__ int unpack_c(unsigned long long p, int C) {
  return C - (int)(unsigned)(p & 0xffffffffu);
}

// base * w for one element. pos = (y == 1)
__device__ __forceinline__ float base_w(float xv, bool pos) {
  float p = 1.f / (1.f + __expf(-xv));          // sigmoid
  float xneg = fminf(1.f - p + CLIP, 1.f);
  float q = pos ? p : xneg;
  float b = __logf(fmaxf(q, EPSV));
  float t = 1.f - q;                             // 1 - pt
  float t2 = t * t;
  float w = pos ? t : t2 * t2;                   // gamma: pos=1, neg=4
  return b * w;
}

// process one float4: accumulate into 4 independent chains, set candidate bit
__device__ __forceinline__ void proc4(float4 X, float4 Y, float4& acc,
                                      unsigned& cmask, int slot) {
  acc.x += base_w(X.x, Y.x > 0.5f);
  acc.y += base_w(X.y, Y.y > 0.5f);
  acc.z += base_w(X.z, Y.z > 0.5f);
  acc.w += base_w(X.w, Y.w > 0.5f);
  float mx = fmaxf(fmaxf(X.x, X.y), fmaxf(X.z, X.w));
  cmask |= (mx > TCAND ? 1u : 0u) << slot;
}

__global__ __launch_bounds__(256) void asl_kernel(
    const float* __restrict__ x, const float* __restrict__ y,
    const int* __restrict__ compost, const int* __restrict__ recycle,
    const int* __restrict__ donate, const int* __restrict__ wl_map,
    float* __restrict__ out, int C, int n1, int n2, int n3)
{
  const int row = blockIdx.x;
  const float* xr = x + (size_t)row * (size_t)C;
  const float* yr = y + (size_t)row * (size_t)C;
  const int tid = threadIdx.x;
  const int lane = tid & 63;
  const int wave = tid >> 6;

  __shared__ int s_has[3];
  __shared__ unsigned s_cnt;
  __shared__ unsigned long long s_cand[MAXC];
  __shared__ float s_sum[4];
  __shared__ unsigned long long s_top[TOPK];

  if (tid < 3) s_has[tid] = 0;
  if (tid == 0) s_cnt = 0;
  __syncthreads();

  // early-issue whitelist gather: load now, test AFTER the stream loop so the
  // scattered-load latency hides under the streaming work
  const int ntot = n1 + n2 + n3;
  float gflag = 0.f; int gwhich = -1;
  if (tid < ntot) {
    int colI;
    if (tid < n1)           { gwhich = 0; colI = compost[tid]; }
    else if (tid < n1 + n2) { gwhich = 1; colI = recycle[tid - n1]; }
    else                    { gwhich = 2; colI = donate[tid - n1 - n2]; }
    gflag = yr[colI];
  }

  float ssc = 0.f;  // scalar-edge contributions

#define PUSH(V, CCOL)                                                     \
  do {                                                                    \
    unsigned _i = atomicAdd(&s_cnt, 1u);                                  \
    if (_i < MAXC) s_cand[_i] = pack_vc((V), (CCOL), C);                  \
  } while (0)
#define PROC_DIRECT(XV, YV, COL)                                          \
  do {                                                                    \
    float _xv = (XV);                                                     \
    ssc += base_w(_xv, (YV) > 0.5f);                                      \
    if (_xv > TCAND) PUSH(_xv, (COL));                                    \
  } while (0)

  // alignment prologue: make float4 base 16B-aligned (row*C mod 4 varies)
  int lead = (int)((4u - ((unsigned)((size_t)row * (size_t)C) & 3u)) & 3u);
  if (lead > C) lead = C;
  for (int col = tid; col < lead; col += 256) PROC_DIRECT(xr[col], yr[col], col);

  const int nvec = (C - lead) >> 2;
  const float4* __restrict__ x4 = (const float4*)(xr + lead);
  const float4* __restrict__ y4 = (const float4*)(yr + lead);

  float4 sacc = make_float4(0.f, 0.f, 0.f, 0.f);
  unsigned cmask = 0;

  // main loop: 4x unrolled, 8 loads in flight, candidates deferred to a bitmask
  int slotbase = 0;
  for (int base = tid; base < nvec; base += 1024, slotbase += 4) {
    const bool v1 = base + 256 < nvec;
    const bool v2 = base + 512 < nvec;
    const bool v3 = base + 768 < nvec;
    float4 xv0, xv1, xv2, xv3, yv0, yv1, yv2, yv3;
    xv0 = x4[base];                 yv0 = y4[base];
    if (v1) { xv1 = x4[base + 256]; yv1 = y4[base + 256]; }
    if (v2) { xv2 = x4[base + 512]; yv2 = y4[base + 512]; }
    if (v3) { xv3 = x4[base + 768]; yv3 = y4[base + 768]; }
    proc4(xv0, yv0, sacc, cmask, slotbase + 0);
    if (v1) proc4(xv1, yv1, sacc, cmask, slotbase + 1);
    if (v2) proc4(xv2, yv2, sacc, cmask, slotbase + 2);
    if (v3) proc4(xv3, yv3, sacc, cmask, slotbase + 3);
  }

  // scalar tail
  for (int col = lead + nvec * 4 + tid; col < C; col += 256)
    PROC_DIRECT(xr[col], yr[col], col);

  // flush whitelist flags (benign write-1 races)
  if (gwhich >= 0 && gflag > 0.5f) s_has[gwhich] = 1;
  for (int i = 256 + tid; i < ntot; i += 256) {  // generic remainder (empty here)
    int which, colI;
    if (i < n1)           { which = 0; colI = compost[i]; }
    else if (i < n1 + n2) { which = 1; colI = recycle[i - n1]; }
    else                  { which = 2; colI = donate[i - n1 - n2]; }
    if (yr[colI] > 0.5f) s_has[which] = 1;
  }

  // materialize candidates from the bitmask (cache-warm reloads, off hot path)
  while (cmask) {
    int b = __ffs(cmask) - 1;
    cmask &= cmask - 1;
    int o = b >> 2, j = b & 3;
    int i = tid + o * 1024 + j * 256;
    float4 X = x4[i];
    int cb = lead + i * 4;
    if (X.x > TCAND) PUSH(X.x, cb + 0);
    if (X.y > TCAND) PUSH(X.y, cb + 1);
    if (X.z > TCAND) PUSH(X.z, cb + 2);
    if (X.w > TCAND) PUSH(X.w, cb + 3);
  }
#undef PROC_DIRECT
#undef PUSH

  // wave reduce the sum
  float sum = ssc + sacc.x + sacc.y + sacc.z + sacc.w;
#pragma unroll
  for (int off = 32; off > 0; off >>= 1) sum += __shfl_xor(sum, off, 64);
  if (lane == 0) s_sum[wave] = sum;
  __syncthreads();

  // wave 0: exact top-10 selection
  if (wave == 0) {
    const unsigned cnt = s_cnt;
    unsigned long long ls[TOPK];   // per-lane sorted (desc) packed list; 0 = pad
#pragma unroll
    for (int s = 0; s < TOPK; s++) ls[s] = 0ULL;

#define INSERT(P)                                                          \
    do {                                                                   \
      unsigned long long _p = (P);                                         \
      if (_p > ls[TOPK - 1]) {                                             \
        _Pragma("unroll")                                                  \
        for (int _s = 0; _s < TOPK; _s++) {                                \
          bool _g = _p > ls[_s];                                           \
          unsigned long long _t = _g ? ls[_s] : _p;                        \
          ls[_s] = _g ? _p : ls[_s];                                       \
          _p = _t;                                                         \
        }                                                                  \
      }                                                                    \
    } while (0)

    if (cnt >= TOPK && cnt <= MAXC) {
      for (unsigned i = lane; i < cnt; i += 64) INSERT(s_cand[i]);
    } else {
      // exact fallback: rescan the (cache-resident) row
      for (int col = lane; col < C; col += 64) INSERT(pack_vc(xr[col], col, C));
    }
#undef INSERT

    // 10 rounds of 64-lane packed max; pop winner (packed values unique)
    for (int r = 0; r < TOPK; r++) {
      unsigned long long mine = ls[0];
      unsigned long long best = mine;
#pragma unroll
      for (int off = 32; off > 0; off >>= 1) {
        unsigned long long o = __shfl_xor(best, off, 64);
        best = (o > best) ? o : best;
      }
      if (lane == 0) s_top[r] = best;
      if (mine == best) {
#pragma unroll
        for (int s = 0; s < TOPK - 1; s++) ls[s] = ls[s + 1];
        ls[TOPK - 1] = 0ULL;
      }
    }
  }
  __syncthreads();

  if (tid == 0) {
    float total = s_sum[0] + s_sum[1] + s_sum[2] + s_sum[3];
    const bool h1 = s_has[0] != 0, h2 = s_has[1] != 0, h3 = s_has[2] != 0;
    const bool gt4 = !(h1 || h2 || h3);

    // rank-sequential multiplier logic (mirrors the lax.scan)
    bool found = false;
    float fr[TOPK];
#pragma unroll
    for (int r = 0; r < TOPK; r++) {
      int col = unpack_c(s_top[r], C);
      int wl = wl_map[col];
      bool in_map = wl > 0;
      bool in_gt = (wl == 1 && h1) || (wl == 2 && h2) ||
                   (wl == 3 && h3) || (wl == 4 && gt4);
      float f = 1.f;
      if (in_map && gt4) f *= ALPHA_OTHER;
      if (in_map && !in_gt && !found) f *= ALPHA1;
      fr[r] = f;
      found = found || (in_map && in_gt);
    }
    const float extra = found ? 1.f : ALPHA1;
#pragma unroll
    for (int r = 0; r < TOPK; r++) {
      float mult = fr[r] * extra;
      if (mult != 1.f) {
        int col = unpack_c(s_top[r], C);
        float xv = unpack_v(s_top[r]);
        float bwv = base_w(xv, yr[col] > 0.5f);
        total += (mult - 1.f) * bwv;
      }
    }
    atomicAdd(out, -total);
  }
}

extern "C" void kernel_launch(void* const* d_in, const int* in_sizes, int n_in,
                              void* d_out, int out_size, void* d_ws, size_t ws_size,
                              hipStream_t stream) {
  const float* x       = (const float*)d_in[0];
  const float* y       = (const float*)d_in[1];
  const int*   compost = (const int*)d_in[2];
  const int*   recycle = (const int*)d_in[3];
  const int*   donate  = (const int*)d_in[4];
  const int*   wl_map  = (const int*)d_in[5];
  float* out = (float*)d_out;

  const int C  = in_sizes[5];
  const int B  = in_sizes[0] / C;
  const int n1 = in_sizes[2], n2 = in_sizes[3], n3 = in_sizes[4];

  hipMemsetAsync(out, 0, sizeof(float), stream);
  asl_kernel<<<B, 256, 0, stream>>>(x, y, compost, recycle, donate, wl_map,
                                    out, C, n1, n2, n3);
}